// Round 1
// baseline (2321.784 us; speedup 1.0000x reference)
//
#include <hip/hip_runtime.h>

#define NB    16
#define GC    100
#define S0    4096
#define S1    4095
#define S2    4094
#define KD    409400     // 100*4094
#define JD    500
#define NCLS  107
#define NSRC  8192
#define NP    65536
#define EDG   4194304
#define E2    2097152

// ws layout (floats)
#define OFF_A   0u          // 6,553,600  : x_p (16,100,4096 view) then conv2 out (x2)
#define OFF_B   6553600u    // 6,553,600  : xf4 (2.10M), then conv1 out, then dense1 partials (4.19M)
#define OFF_AGG 13107200u   // 262,144    : float4 per P-node (sum.xyz, count)
#define OFF_O1  13369344u   // 8,000      : dense1 result 16x500

// ---------------- x_f = x_src @ W_fd^T + b_fd  (rows padded to 4 floats) ----------------
__global__ void __launch_bounds__(256) k_xf(const float* __restrict__ xs,
                                            const float* __restrict__ Wfd,
                                            const float* __restrict__ bfd,
                                            float* __restrict__ xf4) {
    __shared__ float X[16 * 64];
    int t = threadIdx.x;
    int r0 = blockIdx.x * 16;
    ((float4*)X)[t] = ((const float4*)(xs + (size_t)r0 * 64))[t];
    __syncthreads();
#pragma unroll 1
    for (int i = 0; i < 12; ++i) {
        int idx = i * 256 + t;            // 0..3071 = 16 rows x 192 cols
        int rl = idx / 192, c = idx - rl * 192;
        float acc = bfd[c];
        const float4* w4 = (const float4*)(Wfd + c * 64);
        const float4* x4 = (const float4*)(X + rl * 64);
#pragma unroll
        for (int q = 0; q < 16; ++q) {
            float4 w = w4[q], x = x4[q];
            acc += w.x * x.x + w.y * x.y + w.z * x.z + w.w * x.w;
        }
        // logical F-row = src_row*64 + c/3, component = c%3, padded stride 4
        int fr = c / 3, comp = c - fr * 3;
        xf4[(((size_t)(r0 + rl)) * 64 + fr) * 4 + comp] = acc;
    }
}

// ---------------- edge scatter: seg-sum + count (2 edges/thread) ----------------
__global__ void __launch_bounds__(256) k_scat(const int* __restrict__ ei,
                                              const float* __restrict__ xf4,
                                              float4* __restrict__ agg) {
    int g = blockIdx.x * 256 + threadIdx.x;      // < E2/2
    int4 f2 = *(const int4*)(ei + 4 * (size_t)g);          // f(2g), -, f(2g+1), -
    int4 p2 = *(const int4*)(ei + EDG + 4 * (size_t)g);    // p(2g), -, p(2g+1), -
    float4 v0 = *(const float4*)(xf4 + (size_t)f2.x * 4);
    float4 v1 = *(const float4*)(xf4 + (size_t)f2.z * 4);
    float* a0 = (float*)(agg + p2.x);
    atomicAdd(a0 + 0, v0.x);
    atomicAdd(a0 + 1, v0.y);
    atomicAdd(a0 + 2, v0.z);
    atomicAdd(a0 + 3, 1.0f);
    float* a1 = (float*)(agg + p2.z);
    atomicAdd(a1 + 0, v1.x);
    atomicAdd(a1 + 1, v1.y);
    atomicAdd(a1 + 2, v1.z);
    atomicAdd(a1 + 3, 1.0f);
}

// ---------------- x_p = relu(mean @ W_l1^T + b_l1 + x_p0 @ W_r1^T) ----------------
__global__ void __launch_bounds__(256) k_xp(const float4* __restrict__ agg,
                                            const float* __restrict__ xd,
                                            const float* __restrict__ Wl1,
                                            const float* __restrict__ bl1,
                                            const float* __restrict__ Wr1,
                                            float* __restrict__ xp) {
    int idx = blockIdx.x * 256 + threadIdx.x;   // < 6,553,600
    int p = idx / GC, c = idx - p * GC;
    float4 s = agg[p];
    float inv = 1.0f / fmaxf(s.w, 1.0f);
    float ax = s.x * inv, ay = s.y * inv, az = s.z * inv;
    float px = xd[p * 3 + 0], py = xd[p * 3 + 1], pz = xd[p * 3 + 2];
    float y = bl1[c]
            + ax * Wl1[c * 3 + 0] + ay * Wl1[c * 3 + 1] + az * Wl1[c * 3 + 2]
            + px * Wr1[c * 3 + 0] + py * Wr1[c * 3 + 1] + pz * Wr1[c * 3 + 2];
    xp[idx] = fmaxf(y, 0.0f);
}

// ---------------- conv1d k=2, 100->100 ch, relu ----------------
// grid: 512 = 16 n * 4 og * 8 tiles ; block 256 ; thread handles s-pair (s, s+1)
template <int SIN, int SOUT, int INSTR, int OUTSTR>
__global__ void __launch_bounds__(256) k_conv(const float* __restrict__ xin,
                                              const float* __restrict__ Wc,
                                              float* __restrict__ xout) {
    __shared__ float Wl[200 * 28];    // [i*2+k][o_local padded to 28]
    int t = threadIdx.x;
    int bs = blockIdx.x;
    int tile = bs & 7, og = (bs >> 3) & 3, n = bs >> 5;
    for (int e = t; e < 200 * 28; e += 256) {
        int ik = e / 28, ol = e - ik * 28;
        float w = 0.0f;
        if (ol < 25) w = Wc[(og * 25 + ol) * 200 + ik];
        Wl[e] = w;
    }
    __syncthreads();

    int s = tile * 512 + 2 * t;
    float2 acc[28];
#pragma unroll
    for (int o = 0; o < 28; ++o) acc[o] = make_float2(0.f, 0.f);

    const float* xb = xin + (size_t)(n * 100) * INSTR;
#pragma unroll 2
    for (int i = 0; i < 100; ++i) {
        const float* xr = xb + (size_t)i * INSTR;
        // contiguous vector loads; out-of-range lanes only ever feed never-written outputs,
        // and the <=2-float overrun past the last row stays inside ws. Mask for safety.
        float2 v01 = *(const float2*)(xr + s);
        float2 v23 = *(const float2*)(xr + s + 2);
        float a0 = (s     < SIN) ? v01.x : 0.f;
        float a1 = (s + 1 < SIN) ? v01.y : 0.f;
        float a2 = (s + 2 < SIN) ? v23.x : 0.f;
#pragma unroll
        for (int m = 0; m < 7; ++m) {
            float4 w0 = *(const float4*)&Wl[(2 * i) * 28 + 4 * m];
            float4 w1 = *(const float4*)&Wl[(2 * i + 1) * 28 + 4 * m];
            acc[4 * m + 0].x += w0.x * a0 + w1.x * a1;  acc[4 * m + 0].y += w0.x * a1 + w1.x * a2;
            acc[4 * m + 1].x += w0.y * a0 + w1.y * a1;  acc[4 * m + 1].y += w0.y * a1 + w1.y * a2;
            acc[4 * m + 2].x += w0.z * a0 + w1.z * a1;  acc[4 * m + 2].y += w0.z * a1 + w1.z * a2;
            acc[4 * m + 3].x += w0.w * a0 + w1.w * a1;  acc[4 * m + 3].y += w0.w * a1 + w1.w * a2;
        }
    }
    size_t ob = (size_t)(n * 100 + og * 25) * OUTSTR;
#pragma unroll
    for (int ol = 0; ol < 25; ++ol) {
        size_t o = ob + (size_t)ol * OUTSTR;
        float v0 = fmaxf(acc[ol].x, 0.f), v1 = fmaxf(acc[ol].y, 0.f);
        if (s + 1 < SOUT) {
            *(float2*)&xout[o + s] = make_float2(v0, v1);
        } else if (s < SOUT) {
            xout[o + s] = v0;
        }
    }
}

// ---------------- dense1: partial[b][n][j] = sum_{k in block b} x2[n][k] * Wd1[j][k] ----------------
// 512 blocks x 800 k each; KS=16 per stage; register double-buffered staging.
#define ROWW 516
__global__ void __launch_bounds__(256, 2) k_dense1(const float* __restrict__ Wd1,
                                                   const float* __restrict__ x2,
                                                   float* __restrict__ part) {
    __shared__ float Wl[16 * ROWW];   // [kk][j] transposed, 33 KB
    __shared__ float Xl[16 * 16];     // [kk][n]
    int t = threadIdx.x;
    int l = t & 63, w = t >> 6;
    int c4 = t & 3, j0 = t >> 2;      // staging coords: k-quad, j-base

    float4 accA[16], accB[16];
#pragma unroll
    for (int n = 0; n < 16; ++n) {
        accA[n] = make_float4(0.f, 0.f, 0.f, 0.f);
        accB[n] = make_float4(0.f, 0.f, 0.f, 0.f);
    }

    int kstart = blockIdx.x * 800;

    float4 wv[8];                      // W stage registers (double-buffer vs LDS)
    float4 xv = make_float4(0.f, 0.f, 0.f, 0.f);

    auto LOADSTAGE = [&](int ks) {
        int kb = kstart + ks * 16;
        int k = kb + 4 * c4;
#pragma unroll
        for (int u = 0; u < 8; ++u) {
            int j = j0 + 64 * u;
            float4 v = make_float4(0.f, 0.f, 0.f, 0.f);
            if (j < JD) {
                const float* wp = Wd1 + (size_t)j * KD + k;
                if (k + 3 < KD) v = *(const float4*)wp;
                else {
                    if (k + 0 < KD) v.x = wp[0];
                    if (k + 1 < KD) v.y = wp[1];
                    if (k + 2 < KD) v.z = wp[2];
                }
            }
            wv[u] = v;
        }
        if (t < 64) {
            int n = t >> 2, kq = t & 3;
            int kx = kb + 4 * kq;
            const float* xr = x2 + (size_t)n * KD + kx;
            float4 v = make_float4(0.f, 0.f, 0.f, 0.f);
            if (kx + 3 < KD) v = *(const float4*)xr;
            else {
                if (kx + 0 < KD) v.x = xr[0];
                if (kx + 1 < KD) v.y = xr[1];
                if (kx + 2 < KD) v.z = xr[2];
            }
            xv = v;
        }
    };

    LOADSTAGE(0);
#pragma unroll 1
    for (int ks = 0; ks < 50; ++ks) {
        __syncthreads();               // previous compute done with LDS
        // drain staged regs -> LDS
#pragma unroll
        for (int u = 0; u < 8; ++u) {
            int j = j0 + 64 * u;
            Wl[(4 * c4 + 0) * ROWW + j] = wv[u].x;
            Wl[(4 * c4 + 1) * ROWW + j] = wv[u].y;
            Wl[(4 * c4 + 2) * ROWW + j] = wv[u].z;
            Wl[(4 * c4 + 3) * ROWW + j] = wv[u].w;
        }
        if (t < 64) {
            int n = t >> 2, kq = t & 3;
            Xl[(4 * kq + 0) * 16 + n] = xv.x;
            Xl[(4 * kq + 1) * 16 + n] = xv.y;
            Xl[(4 * kq + 2) * 16 + n] = xv.z;
            Xl[(4 * kq + 3) * 16 + n] = xv.w;
        }
        __syncthreads();
        if (ks + 1 < 50) LOADSTAGE(ks + 1);   // prefetch next stage; latency hides under compute
        // compute: wave w handles kk = w*4 .. w*4+3
#pragma unroll
        for (int q = 0; q < 4; ++q) {
            int kk = w * 4 + q;
            float4 wa = *(const float4*)&Wl[kk * ROWW + 4 * l];
            float4 wb = *(const float4*)&Wl[kk * ROWW + 256 + 4 * l];
            const float4* xk = (const float4*)&Xl[kk * 16];
            float4 x0 = xk[0], x1 = xk[1], x2v = xk[2], x3 = xk[3];
            float xs[16] = {x0.x, x0.y, x0.z, x0.w, x1.x, x1.y, x1.z, x1.w,
                            x2v.x, x2v.y, x2v.z, x2v.w, x3.x, x3.y, x3.z, x3.w};
#pragma unroll
            for (int n = 0; n < 16; ++n) {
                float xvn = xs[n];
                accA[n].x += wa.x * xvn; accA[n].y += wa.y * xvn;
                accA[n].z += wa.z * xvn; accA[n].w += wa.w * xvn;
                accB[n].x += wb.x * xvn; accB[n].y += wb.y * xvn;
                accB[n].z += wb.z * xvn; accB[n].w += wb.w * xvn;
            }
        }
    }
    // block reduce via LDS (reuse Wl as 16x512), then coalesced partial store (no global atomics)
    __syncthreads();
    float* red = Wl;
    for (int r = t; r < 8192; r += 256) red[r] = 0.f;
    __syncthreads();
#pragma unroll
    for (int n = 0; n < 16; ++n) {
        atomicAdd(&red[n * 512 + 4 * l + 0], accA[n].x);
        atomicAdd(&red[n * 512 + 4 * l + 1], accA[n].y);
        atomicAdd(&red[n * 512 + 4 * l + 2], accA[n].z);
        atomicAdd(&red[n * 512 + 4 * l + 3], accA[n].w);
        atomicAdd(&red[n * 512 + 256 + 4 * l + 0], accB[n].x);
        atomicAdd(&red[n * 512 + 256 + 4 * l + 1], accB[n].y);
        atomicAdd(&red[n * 512 + 256 + 4 * l + 2], accB[n].z);
        atomicAdd(&red[n * 512 + 256 + 4 * l + 3], accB[n].w);
    }
    __syncthreads();
    for (int r = t; r < 8192; r += 256)
        part[(size_t)blockIdx.x * 8192 + r] = red[r];
}

// ---------------- reduce dense1 partials: out1[n][j] = sum_b part[b][n*512+j] ----------------
__global__ void __launch_bounds__(256) k_red(const float* __restrict__ part,
                                             float* __restrict__ out1) {
    int r = blockIdx.x * 256 + threadIdx.x;   // < 8192
    int n = r >> 9, j = r & 511;
    float s = 0.f;
#pragma unroll 8
    for (int b = 0; b < 512; ++b)
        s += part[(size_t)b * 8192 + r];
    if (j < JD) out1[n * JD + j] = s;
}

// ---------------- head: relu -> @ W_d2^T -> softmax ----------------
__global__ void __launch_bounds__(128) k_head(const float* __restrict__ out1,
                                              const float* __restrict__ Wd2,
                                              float* __restrict__ out) {
    __shared__ float sj[500];
    __shared__ float lg[128];
    __shared__ float mx, sm;
    int n = blockIdx.x, t = threadIdx.x;
    for (int j = t; j < JD; j += 128) sj[j] = fmaxf(out1[n * JD + j], 0.f);
    __syncthreads();
    float acc = 0.f;
    if (t < NCLS) {
        const float4* w4 = (const float4*)(Wd2 + (size_t)t * JD);
        const float4* s4 = (const float4*)sj;
        for (int q = 0; q < 125; ++q) {
            float4 w = w4[q], x = s4[q];
            acc += w.x * x.x + w.y * x.y + w.z * x.z + w.w * x.w;
        }
    }
    lg[t] = (t < NCLS) ? acc : -1e30f;
    __syncthreads();
    if (t == 0) {
        float m = -1e30f;
        for (int cc = 0; cc < NCLS; ++cc) m = fmaxf(m, lg[cc]);
        mx = m;
    }
    __syncthreads();
    float e = 0.f;
    if (t < NCLS) { e = __builtin_expf(lg[t] - mx); lg[t] = e; }
    __syncthreads();
    if (t == 0) {
        float s = 0.f;
        for (int cc = 0; cc < NCLS; ++cc) s += lg[cc];
        sm = s;
    }
    __syncthreads();
    if (t < NCLS) out[(size_t)n * NCLS + t] = e / sm;
}

extern "C" void kernel_launch(void* const* d_in, const int* in_sizes, int n_in,
                              void* d_out, int out_size, void* d_ws, size_t ws_size,
                              hipStream_t stream) {
    const float* xsrc = (const float*)d_in[0];
    const float* xdst = (const float*)d_in[1];
    const int*   ei   = (const int*)d_in[2];
    const float* Wfd  = (const float*)d_in[3];
    const float* bfd  = (const float*)d_in[4];
    const float* Wl1  = (const float*)d_in[5];
    const float* bl1  = (const float*)d_in[6];
    const float* Wr1  = (const float*)d_in[7];
    // d_in[8..10] = W_l2, b_l2, W_r2 : dead code in the reference (x_f layer-2 unused)
    const float* Wc1  = (const float*)d_in[11];
    const float* Wc2  = (const float*)d_in[12];
    const float* Wd1  = (const float*)d_in[13];
    const float* Wd2  = (const float*)d_in[14];

    float* ws = (float*)d_ws;
    float*  A   = ws + OFF_A;
    float*  B   = ws + OFF_B;
    float4* AGG = (float4*)(ws + OFF_AGG);
    float*  O1  = ws + OFF_O1;
    float*  OUT = (float*)d_out;

    (void)hipMemsetAsync(AGG, 0, NP * sizeof(float4), stream);

    k_xf<<<NSRC / 16, 256, 0, stream>>>(xsrc, Wfd, bfd, B);           // B = xf4 (padded rows)
    k_scat<<<E2 / 2 / 256, 256, 0, stream>>>(ei, B, AGG);
    k_xp<<<(NP * GC) / 256, 256, 0, stream>>>(AGG, xdst, Wl1, bl1, Wr1, A);
    k_conv<S0, S1, 4096, 4096><<<512, 256, 0, stream>>>(A, Wc1, B);   // overwrites xf4 (consumed)
    k_conv<S1, S2, 4096, 4094><<<512, 256, 0, stream>>>(B, Wc2, A);
    k_dense1<<<512, 256, 0, stream>>>(Wd1, A, B);                     // partials into B (conv1 out consumed)
    k_red<<<32, 256, 0, stream>>>(B, O1);
    k_head<<<NB, 128, 0, stream>>>(O1, Wd2, OUT);
}